// Round 8
// baseline (3663.710 us; speedup 1.0000x reference)
//
#include <hip/hip_runtime.h>
#include <math.h>
#include <float.h>

#define NB     64      // batch
#define S_EN   50
#define S_DE   50
#define EMB_E  64
#define EMB_D  32
#define HID    32
#define G4     128     // 4*H
#define DE_VSZ 19000
#define OUT_B  (S_DE * DE_VSZ)

#define NG     4       // batch groups
#define JB     16      // batches per group
#define NSL    60      // vocab slices per group
#define NRS    320     // fc rows per slice (60*320 = 19200 >= 19000)
#define NBLK   (NG * NSL)   // 240 blocks <= 256 CUs -> co-resident by capacity
#define NTHR   640     // 10 waves; fc: (row 0..319) x (batch-octet 0..1)
#define WST    100     // LDS weight row stride (400 B, 16B-aligned)
#define POLL_CAP 200000 // bounded poll: failure -> terminating wrong answer

typedef unsigned long long ull;
typedef float floatx4 __attribute__((ext_vector_type(4)));   // nontemporal-legal

__device__ __forceinline__ float sigmoidf_(float x) { return 1.0f / (1.0f + expf(-x)); }

// monotone float->uint: a<b <=> ordf(a)<ordf(b)
__device__ __forceinline__ unsigned ordf_(float f) {
    unsigned u = __float_as_uint(f);
    return (u & 0x80000000u) ? ~u : (u | 0x80000000u);
}

// Grid: 240 blocks = 4 batch-groups x 60 vocab slices. Block (g,isl):
//  - redundantly runs the LSTM for its group's 16 batches (bitwise identical
//    across the 60 slice-siblings),
//  - holds ONE fc row per thread in VGPRs (loaded once -> ZERO per-step
//    fc_W traffic; round-7 spent ~4.2us/step re-streaming fc_W from L2),
//  - computes that row's logit for 8 batches (its octet).
// SINGLE-HOP MAX-COMBINE rendezvous (all links are atomic RMWs at the device
// coherence point -- the r5 lesson; no fences anywhere):
//  publish: 16 lanes atomic_fetch_max key -> cells[par][g][b]
//           (key = [step:6|ordf:32|~idx:15]; later steps always win);
//           __syncthreads (drains vmcnt -> maxes visible);
//           lane0 fetch_add(1) on cumulative counter[g].
//  consume: lane0 spins fetch_add(0) counter >= 60*s; 16 lanes RMW-read cells.
// Chain-gating: a block publishes s+2 (same parity as s) only after counter
// >= 60*(s+1), which requires all 60 siblings consumed step s -> parity-2 is
// safe and tag==s is guaranteed at read time. POLL_CAP keeps failures finite.
__global__ __launch_bounds__(NTHR, 3) void seq2seq_gmax(
    const int*   __restrict__ en_batch, const int* __restrict__ en_lens,
    const int*   __restrict__ de_batch,
    const float* __restrict__ en_emb,
    const float* __restrict__ eWih, const float* __restrict__ eWhh,
    const float* __restrict__ ebih, const float* __restrict__ ebhh,
    const float* __restrict__ de_emb,
    const float* __restrict__ dWih, const float* __restrict__ dWhh,
    const float* __restrict__ dbih, const float* __restrict__ dbhh,
    const float* __restrict__ fcW,  const float* __restrict__ fcb,
    float*       __restrict__ out,
    ull* cells,   // (2, NG, JB) max-combined keys, parity-buffered
    ull* cnt)     // (NG,) cumulative publish counters, stride 16 ull (128 B)
{
    const int tid  = threadIdx.x;
    const int lane = tid & 63;
    const int wvi  = tid >> 6;           // wave 0..9
    const int bx   = blockIdx.x;
    const int g    = bx & 3;             // batch group
    const int isl  = bx >> 2;            // vocab slice 0..59

    __shared__ __align__(16) float s_w[G4 * WST];   // 51.2 KB enc/dec weights
    __shared__ __align__(16) float s_xh[JB][104];   // x|h per batch (enc h@64, dec h@32)
    __shared__ ull  s_red[10 * JB];                 // per-wave per-batch keys
    __shared__ int  s_tok[JB];
    __shared__ int  s_len[JB];

    // ---- zero out[:, 0, :] (wave-contiguous, non-temporal) ----
    for (int idx = bx * NTHR + tid; idx < NB * (DE_VSZ / 4); idx += NBLK * NTHR) {
        const int bb = idx / (DE_VSZ / 4);
        const int qq = idx - bb * (DE_VSZ / 4);
        const floatx4 z = {0.f, 0.f, 0.f, 0.f};
        __builtin_nontemporal_store(z,
            (floatx4*)(out + (size_t)bb * OUT_B + (size_t)qq * 4));
    }

    // ---- stage encoder weights: row r = eWih[r][0..63] | eWhh[r][0..31] ----
    for (int idx = tid; idx < G4 * 96; idx += NTHR) {
        const int row = idx / 96, k = idx - row * 96;
        s_w[row * WST + k] = (k < EMB_E) ? eWih[row * EMB_E + k]
                                         : eWhh[row * HID + (k - EMB_E)];
    }
    if (tid < JB) {
        s_len[tid] = en_lens[g * JB + tid];
        s_tok[tid] = de_batch[(g * JB + tid) * S_DE + 0];
    }

    // LSTM thread mapping: (jb = tid>>5, u = tid&31) for tid < 512.
    const int jb = tid >> 5;
    const int u  = tid & 31;
    float ebs0=0,ebs1=0,ebs2=0,ebs3=0, dbs0=0,dbs1=0,dbs2=0,dbs3=0;
    float creg = 0.f;
    if (tid < JB * HID) {
        ebs0 = ebih[u]      + ebhh[u];
        ebs1 = ebih[32 + u] + ebhh[32 + u];
        ebs2 = ebih[64 + u] + ebhh[64 + u];
        ebs3 = ebih[96 + u] + ebhh[96 + u];
        dbs0 = dbih[u]      + dbhh[u];
        dbs1 = dbih[32 + u] + dbhh[32 + u];
        dbs2 = dbih[64 + u] + dbhh[64 + u];
        dbs3 = dbih[96 + u] + dbhh[96 + u];
        s_xh[jb][64 + u] = 0.f;          // encoder h init
    }

    // ---- fc: one (row, batch-octet) per thread; weights live in VGPRs ----
    const int  frow   = tid >> 1;                 // 0..319
    const int  hf     = tid & 1;                  // batch octet
    const int  r      = isl * NRS + frow;
    const bool rvalid = (r < DE_VSZ);
    float fw[32]; float fb = 0.f;
    {
        const float4* w4p = (const float4*)&fcW[(size_t)(rvalid ? r : 0) * HID];
        #pragma unroll
        for (int c = 0; c < 8; ++c) {
            const float4 v = w4p[c];
            fw[c*4+0] = v.x; fw[c*4+1] = v.y; fw[c*4+2] = v.z; fw[c*4+3] = v.w;
        }
        if (rvalid) fb = fcb[r];
    }
    __syncthreads();

    int maxlen = 1;
    for (int j = 0; j < JB; ++j) maxlen = max(maxlen, s_len[j]);
    const int mylen = (tid < JB * HID) ? s_len[jb] : 0;

    // ---- encoder: 16 batches, mask t < len[jb] (matches jnp.where(valid)) ----
    for (int t = 0; t < maxlen; ++t) {
        if (tid < JB * 16) {
            const int jj = tid >> 4, q = tid & 15;
            const int etok = en_batch[(g * JB + jj) * S_EN + t];
            *(float4*)&s_xh[jj][q * 4] = *(const float4*)&en_emb[(size_t)etok * EMB_E + q * 4];
        }
        __syncthreads();
        float cnew = 0.f, hnew = 0.f;
        if (tid < JB * HID) {
            float a0 = ebs0, a1 = ebs1, a2 = ebs2, a3 = ebs3;
            #pragma unroll
            for (int kc = 0; kc < 24; ++kc) {
                const float4 xh = *(const float4*)&s_xh[jb][kc * 4];
                const float4 w0 = *(const float4*)&s_w[(u     ) * WST + kc * 4];
                const float4 w1 = *(const float4*)&s_w[(u + 32) * WST + kc * 4];
                const float4 w2 = *(const float4*)&s_w[(u + 64) * WST + kc * 4];
                const float4 w3 = *(const float4*)&s_w[(u + 96) * WST + kc * 4];
                a0 = fmaf(xh.x,w0.x,a0); a0 = fmaf(xh.y,w0.y,a0); a0 = fmaf(xh.z,w0.z,a0); a0 = fmaf(xh.w,w0.w,a0);
                a1 = fmaf(xh.x,w1.x,a1); a1 = fmaf(xh.y,w1.y,a1); a1 = fmaf(xh.z,w1.z,a1); a1 = fmaf(xh.w,w1.w,a1);
                a2 = fmaf(xh.x,w2.x,a2); a2 = fmaf(xh.y,w2.y,a2); a2 = fmaf(xh.z,w2.z,a2); a2 = fmaf(xh.w,w2.w,a2);
                a3 = fmaf(xh.x,w3.x,a3); a3 = fmaf(xh.y,w3.y,a3); a3 = fmaf(xh.z,w3.z,a3); a3 = fmaf(xh.w,w3.w,a3);
            }
            const float ii = sigmoidf_(a0), ff = sigmoidf_(a1);
            const float gg = tanhf(a2),     oo = sigmoidf_(a3);
            cnew = ff * creg + ii * gg;
            hnew = oo * tanhf(cnew);
        }
        __syncthreads();
        if (tid < JB * HID && t < mylen) {
            creg = cnew;
            s_xh[jb][64 + u] = hnew;
        }
        __syncthreads();
    }

    // ---- handoff: h -> decoder slot [32+u]; restage decoder weights ----
    float hcur = 0.f;
    if (tid < JB * HID) hcur = s_xh[jb][64 + u];   // read [64..95]
    for (int idx = tid; idx < G4 * 64; idx += NTHR) {
        const int row = idx >> 6, k = idx & 63;
        s_w[row * WST + k] = (k < HID) ? dWih[row * HID + k]
                                       : dWhh[row * HID + (k - HID)];
    }
    if (tid < JB * HID) s_xh[jb][32 + u] = hcur;   // write [32..63] (disjoint)
    __syncthreads();

    // ---- decoder: 49 steps ----
    for (int s = 1; s < S_DE; ++s) {
        // (a) x = de_emb[tok]
        if (tid < JB * 8) {
            const int jj = tid >> 3, q = tid & 7;
            const int tk_ = s_tok[jj];
            *(float4*)&s_xh[jj][q * 4] = *(const float4*)&de_emb[(size_t)tk_ * EMB_D + q * 4];
        }
        __syncthreads();

        // (b) gates fully in regs (thread owns (jb,u): 4 gates + cell state)
        float hnew = 0.f;
        if (tid < JB * HID) {
            float a0 = dbs0, a1 = dbs1, a2 = dbs2, a3 = dbs3;
            #pragma unroll
            for (int kc = 0; kc < 16; ++kc) {
                const float4 xh = *(const float4*)&s_xh[jb][kc * 4];
                const float4 w0 = *(const float4*)&s_w[(u     ) * WST + kc * 4];
                const float4 w1 = *(const float4*)&s_w[(u + 32) * WST + kc * 4];
                const float4 w2 = *(const float4*)&s_w[(u + 64) * WST + kc * 4];
                const float4 w3 = *(const float4*)&s_w[(u + 96) * WST + kc * 4];
                a0 = fmaf(xh.x,w0.x,a0); a0 = fmaf(xh.y,w0.y,a0); a0 = fmaf(xh.z,w0.z,a0); a0 = fmaf(xh.w,w0.w,a0);
                a1 = fmaf(xh.x,w1.x,a1); a1 = fmaf(xh.y,w1.y,a1); a1 = fmaf(xh.z,w1.z,a1); a1 = fmaf(xh.w,w1.w,a1);
                a2 = fmaf(xh.x,w2.x,a2); a2 = fmaf(xh.y,w2.y,a2); a2 = fmaf(xh.z,w2.z,a2); a2 = fmaf(xh.w,w2.w,a2);
                a3 = fmaf(xh.x,w3.x,a3); a3 = fmaf(xh.y,w3.y,a3); a3 = fmaf(xh.z,w3.z,a3); a3 = fmaf(xh.w,w3.w,a3);
            }
            const float ii = sigmoidf_(a0), ff = sigmoidf_(a1);
            const float gg = tanhf(a2),     oo = sigmoidf_(a3);
            creg = ff * creg + ii * gg;
            hnew = oo * tanhf(creg);
        }
        __syncthreads();
        if (tid < JB * HID) s_xh[jb][32 + u] = hnew;
        __syncthreads();

        // (c) fc: thread's VGPR row x 8 batches (its octet); h broadcast from LDS
        float accv[8];
        #pragma unroll
        for (int j8 = 0; j8 < 8; ++j8) {
            const int jb_ = hf * 8 + j8;
            const float* hj = &s_xh[jb_][32];
            float a = fb;
            #pragma unroll
            for (int kc = 0; kc < 8; ++kc) {
                const float4 h4 = *(const float4*)&hj[kc * 4];
                a = fmaf(fw[kc*4+0], h4.x, a);
                a = fmaf(fw[kc*4+1], h4.y, a);
                a = fmaf(fw[kc*4+2], h4.z, a);
                a = fmaf(fw[kc*4+3], h4.w, a);
            }
            accv[j8] = a;
        }

        const int par = s & 1;
        // (d) publish FIRST (key reduce -> 16 atomicMax -> barrier -> counter)
        if (s < S_DE - 1) {
            #pragma unroll
            for (int j8 = 0; j8 < 8; ++j8) {
                ull kj = rvalid ? (((ull)ordf_(accv[j8]) << 15) | (unsigned)((~r) & 0x7FFF)) : 0ull;
                #pragma unroll
                for (int off = 2; off <= 32; off <<= 1) {   // reduce same-octet lanes
                    const ull ok = __shfl_xor(kj, off);
                    if (ok > kj) kj = ok;
                }
                if (lane < 2) s_red[(wvi * 2 + hf) * 8 + j8] = kj;
            }
            __syncthreads();
            if (tid < JB) {            // batch tid: reduce 10 waves, max-combine
                ull m = s_red[(tid >> 3) * 8 + (tid & 7)];
                for (int w = 1; w < 10; ++w) {
                    const ull k2 = s_red[(w * 2 + (tid >> 3)) * 8 + (tid & 7)];
                    if (k2 > m) m = k2;
                }
                (void)__hip_atomic_fetch_max(&cells[(size_t)par * (NG*JB) + g * JB + tid],
                                             ((ull)s << 47) | m,
                                             __ATOMIC_RELAXED, __HIP_MEMORY_SCOPE_AGENT);
            }
            __syncthreads();           // full vmcnt drain -> maxes visible
            if (tid == 0)
                (void)__hip_atomic_fetch_add(&cnt[(size_t)g * 16], 1ull,
                                             __ATOMIC_RELAXED, __HIP_MEMORY_SCOPE_AGENT);
        }

        // (e) non-temporal logit stores (overlap siblings' polls; L2 stays clean)
        {
            float* od = out + (size_t)(g * JB) * OUT_B + (size_t)s * DE_VSZ + r;
            #pragma unroll
            for (int j8 = 0; j8 < 8; ++j8) {
                const int jb_ = hf * 8 + j8;
                if (rvalid)
                    __builtin_nontemporal_store(accv[j8], &od[(size_t)jb_ * OUT_B]);
            }
        }
        if (s == S_DE - 1) break;   // final step: logits stored, no token needed

        // (f) wave0: spin one RMW on counter until >= 60*s, then read 16 cells
        if (wvi == 0) {
            const ull need = (ull)NSL * (ull)s;
            int done = 0;
            for (int iter = 0; iter < POLL_CAP; ++iter) {
                ull c = 0;
                if (lane == 0)
                    c = __hip_atomic_fetch_add(&cnt[(size_t)g * 16], 0ull,
                                               __ATOMIC_RELAXED, __HIP_MEMORY_SCOPE_AGENT);
                done = __shfl((c >= need) ? 1 : 0, 0);
                if (done) break;
                __builtin_amdgcn_s_sleep(1);
            }
            if (lane < JB) {
                const ull v = __hip_atomic_fetch_add(&cells[(size_t)par * (NG*JB) + g * JB + lane],
                                                     0ull, __ATOMIC_RELAXED, __HIP_MEMORY_SCOPE_AGENT);
                s_tok[lane] = (int)((~(unsigned)v) & 0x7FFF);
            }
        }
        __syncthreads();
    }
}

extern "C" void kernel_launch(void* const* d_in, const int* in_sizes, int n_in,
                              void* d_out, int out_size, void* d_ws, size_t ws_size,
                              hipStream_t stream) {
    (void)in_sizes; (void)n_in; (void)out_size; (void)ws_size;
    const int*   en_batch = (const int*)  d_in[0];
    const int*   en_lens  = (const int*)  d_in[1];
    const int*   de_batch = (const int*)  d_in[2];
    const float* en_emb   = (const float*)d_in[3];
    const float* eWih     = (const float*)d_in[4];
    const float* eWhh     = (const float*)d_in[5];
    const float* ebih     = (const float*)d_in[6];
    const float* ebhh     = (const float*)d_in[7];
    const float* de_emb   = (const float*)d_in[8];
    const float* dWih     = (const float*)d_in[9];
    const float* dWhh     = (const float*)d_in[10];
    const float* dbih     = (const float*)d_in[11];
    const float* dbhh     = (const float*)d_in[12];
    const float* fcW      = (const float*)d_in[13];
    const float* fcb      = (const float*)d_in[14];
    float* out = (float*)d_out;

    ull* cells = (ull*)d_ws;                        // 2*4*16*8 = 1 KB
    ull* cnt   = (ull*)((char*)d_ws + 1024);        // 4 counters, 128 B apart
    (void)hipMemsetAsync(d_ws, 0, 4096, stream);    // tag 0 / count 0

    seq2seq_gmax<<<NBLK, NTHR, 0, stream>>>(
        en_batch, en_lens, de_batch, en_emb, eWih, eWhh, ebih, ebhh,
        de_emb, dWih, dWhh, dbih, dbhh, fcW, fcb, out, cells, cnt);
}